// Round 9
// baseline (354.693 us; speedup 1.0000x reference)
//
#include <hip/hip_runtime.h>

typedef _Float16 half8 __attribute__((ext_vector_type(8)));
typedef __attribute__((ext_vector_type(4))) float f32x4;

__device__ __forceinline__ unsigned short f2h(float f) {
    _Float16 h = (_Float16)f;
    return *(unsigned short*)&h;
}
__device__ __forceinline__ float h2f(unsigned short u) {
    _Float16 h = *(_Float16*)&u;
    return (float)h;
}

// ---------- merged prep: x->f16, W1/W2 images, hist zero ----------

__device__ __forceinline__ void wprep_body(
    const float* __restrict__ W, const float* __restrict__ root,
    unsigned short* __restrict__ wb, int dout, int idx)
{
    int c = idx / (64 * dout);
    int rme = idx % (64 * dout);
    int kk = rme / dout;
    int j = rme % dout;
    float f = (c == 0) ? root[kk * dout + j]
                       : W[(size_t)(c - 1) * 64 * dout + kk * dout + j];
    wb[(size_t)c * dout * 72 + (size_t)j * 72 + kk] = f2h(f);
}

__global__ __launch_bounds__(256) void prep_kernel(
    const float* __restrict__ x, unsigned short* __restrict__ xh, int n8,
    const float* __restrict__ W1, const float* __restrict__ root1,
    unsigned short* __restrict__ wb1,
    const float* __restrict__ W2, const float* __restrict__ root2,
    unsigned short* __restrict__ wb2,
    int* __restrict__ hist, int nhist4)
{
    int id = blockIdx.x * 256 + threadIdx.x;
    if (id < n8) {                       // x -> f16, 8 elems/thread
        const f32x4* p = (const f32x4*)(x + (size_t)id * 8);
        f32x4 u = p[0], v = p[1];
        half8 o;
#pragma unroll
        for (int j = 0; j < 4; ++j) {
            o[j] = (_Float16)u[j];
            o[j + 4] = (_Float16)v[j];
        }
        *(half8*)(xh + (size_t)id * 8) = o;
        return;
    }
    id -= n8;
    if (id < 9 * 64 * 64) { wprep_body(W1, root1, wb1, 64, id); return; }
    id -= 9 * 64 * 64;
    if (id < 9 * 64 * 32) { wprep_body(W2, root2, wb2, 32, id); return; }
    id -= 9 * 64 * 32;
    if (id < nhist4) ((int4*)hist)[id] = make_int4(0, 0, 0, 0);
}

// ---------- preprocessing: counting sort by key = dst*8 + rel ----------

__global__ __launch_bounds__(256) void hist8_kernel(
    const int* __restrict__ dst, const int* __restrict__ et,
    int* __restrict__ hist, int E)
{
    int e = blockIdx.x * 256 + threadIdx.x;
    if (e < E) atomicAdd(&hist[dst[e] * 8 + et[e]], 1);
}

#define SCAN_TILE 4096
__global__ __launch_bounds__(1024) void scanA_kernel(
    const int* __restrict__ hist, int* __restrict__ bstart,
    int* __restrict__ partial, int nkeys)
{
    __shared__ int wsum[16];
    const int t = threadIdx.x;
    const int lane = t & 63, w = t >> 6;
    const int base = blockIdx.x * SCAN_TILE + t * 4;
    int v[4];
    int s = 0;
#pragma unroll
    for (int i = 0; i < 4; ++i) {
        v[i] = (base + i < nkeys) ? hist[base + i] : 0;
        s += v[i];
    }
    int inc = s;
#pragma unroll
    for (int off = 1; off < 64; off <<= 1) {
        int u = __shfl_up(inc, off);
        if (lane >= off) inc += u;
    }
    if (lane == 63) wsum[w] = inc;
    __syncthreads();
    if (w == 0 && lane < 16) {
        int ws = wsum[lane];
        int winc = ws;
#pragma unroll
        for (int off = 1; off < 16; off <<= 1) {
            int u = __shfl_up(winc, off);
            if (lane >= off) winc += u;
        }
        wsum[lane] = winc - ws;   // exclusive
    }
    __syncthreads();
    int run = wsum[w] + (inc - s);
#pragma unroll
    for (int i = 0; i < 4; ++i) {
        if (base + i < nkeys) bstart[base + i] = run;
        run += v[i];
    }
    if (t == 1023) partial[blockIdx.x] = run;   // block total
}

__global__ __launch_bounds__(64) void scanB_kernel(
    const int* __restrict__ partial, int* __restrict__ pscan,
    int* __restrict__ bstart_end, int nblk)
{
    const int lane = threadIdx.x;
    int running = 0;
    for (int b = 0; b < nblk; b += 64) {
        int i = b + lane;
        int o = (i < nblk) ? partial[i] : 0;
        int v = o;
#pragma unroll
        for (int off = 1; off < 64; off <<= 1) {
            int u = __shfl_up(v, off);
            if (lane >= off) v += u;
        }
        if (i < nblk) pscan[i] = running + v - o;
        running += __shfl(v, 63);
    }
    if (lane == 0) *bstart_end = running;   // == E
}

// scatter: pos = bstart[key] + pscan + (atomicSub(hist)-1).
// Within-segment order is arbitrary (sum is order-independent); hist is dead
// after scanA, so it doubles as the cursor -- no rank array at all.
__global__ __launch_bounds__(256) void scatter_kernel(
    const int* __restrict__ src, const int* __restrict__ dst,
    const int* __restrict__ et, int* __restrict__ hist,
    const int* __restrict__ bstart, const int* __restrict__ pscan,
    unsigned* __restrict__ srt, int E)
{
    int e = blockIdx.x * 256 + threadIdx.x;
    if (e < E) {
        int key = dst[e] * 8 + et[e];
        int r = atomicSub(&hist[key], 1) - 1;
        srt[bstart[key] + pscan[key >> 12] + r] = (unsigned)src[e];
    }
}

// ---------- fused layer: aggregate means into LDS A-tile, then MFMA dense ----------
// Block = 256 threads (4 waves) = 16 nodes; wave w owns 4 nodes (32 segments).
// Agg: lane = feature; per edge one SGPR-base 128B-row gather via asm-volatile
// global_load_ushort with counted s_waitcnt vmcnt(16) + sched_barrier(0).
// ROUND-8 BUG FIX: the old pipeline copied GA<-GB registers while GB's loads
// were still in flight (vmcnt(16) leaves them outstanding); asm loads have no
// compiler-tracked completion, so the v_movs read garbage (absmax 1.15 fail).
// Now: STATIC PING-PONG, no copy -- batches 0..3 alternate GA/GB with all
// buffer indices compile-time; a buffer is consumed only after a wait that
// drains it, and re-issued only two phases after its consume.

template <int DOUT, int RELU, int OUTH>
__global__ __launch_bounds__(256, 6) void fused_kernel(
    const unsigned short* __restrict__ tab,   // (N,64) f16 gather/self table
    const unsigned* __restrict__ srt,         // src per edge (sorted by dst*8+rel)
    const int* __restrict__ bstart,           // (N*8+1) LOCAL scan (pre-pscan)
    const int* __restrict__ pscan,            // per-4096-tile offsets
    const unsigned short* __restrict__ wb,    // (9, DOUT, 72) f16
    const float* __restrict__ bias,
    float* __restrict__ outf,                 // fp32 out (OUTH=0)
    unsigned short* __restrict__ outh,        // f16 out, stride 64 (OUTH=1)
    int n_nodes, int Etot)
{
    __shared__ __align__(16) unsigned short Atile[16 * 600];   // 19.2 KB

    const int t = threadIdx.x;
    const int w = t >> 6, lane = t & 63;
    const int quad = lane >> 4, l16 = lane & 15;
    const int nbt = blockIdx.x * 16;
    const int nb4 = nbt + w * 4;
    const int KEYS = n_nodes * 8;

    // ---- aggregation phase (wave-private rows) ----
    {
        const int nb0 = nb4 * 8;                          // 32 keys for this wave
        int idx = nb0 + lane; if (idx > KEYS) idx = KEYS;
        int lv;
        if (idx < KEYS) lv = bstart[idx] + pscan[idx >> 12];
        else            lv = Etot;
        const int E0 = __builtin_amdgcn_readlane(lv, 0);
        const int E1 = __builtin_amdgcn_readlane(lv, 32);

        // per-segment reciprocal counts (lanes 0..31 valid)
        int cntv = __shfl_down(lv, 1) - lv;
        float rsc = 1.0f / fmaxf((float)cntv, 1.0f);

        // self rows (chunk 0)
#pragma unroll
        for (int i = 0; i < 4; ++i) {
            int node = nb4 + i;
            unsigned short v = 0;
            if (node < n_nodes) v = tab[(size_t)node * 64 + lane];
            Atile[(w * 4 + i) * 600 + lane] = v;
        }

        float acc0 = 0.f, acc1 = 0.f;
        int R = 0;                                        // segment index 0..31
        int bnext = __builtin_amdgcn_readlane(lv, 1);

        auto flushes = [&](int eabs) {
            while (R < 32 && eabs == bnext) {
                float sc = __uint_as_float(
                    __builtin_amdgcn_readlane(__float_as_uint(rsc), R));
                Atile[(w * 4 + (R >> 3)) * 600 + 64 + (R & 7) * 64 + lane] =
                    f2h((acc0 + acc1) * sc);
                acc0 = 0.f; acc1 = 0.f;
                ++R;
                bnext = (R < 31) ? __builtin_amdgcn_readlane(lv, R + 1) : E1;
            }
        };

        const char* tabc = (const char*)tab;
        const unsigned voff = (unsigned)(lane << 1);
        unsigned GA[16], GB[16];

#define ISSUE16(BUF, RECV, KB)                                              \
        _Pragma("unroll")                                                   \
        for (int i_ = 0; i_ < 16; ++i_) {                                   \
            int q_ = __builtin_amdgcn_readlane((int)(RECV), (KB) + i_);     \
            const char* ap_ = tabc + ((size_t)(unsigned)q_ << 7);           \
            asm volatile("global_load_ushort %0, %1, %2"                    \
                         : "=v"(BUF[i_]) : "v"(voff), "s"(ap_));            \
        }
#define WAIT16  asm volatile("s_waitcnt vmcnt(16)" ::: "memory")
#define WAIT0   asm volatile("s_waitcnt vmcnt(0)" ::: "memory")
#define SB      __builtin_amdgcn_sched_barrier(0)
#define CONSUME_FULL(BUF, B)                                                \
        _Pragma("unroll")                                                   \
        for (int i_ = 0; i_ < 16; ++i_) {                                   \
            flushes(base + (B) + i_);                                       \
            if (i_ & 1) acc1 += h2f((unsigned short)BUF[i_]);               \
            else        acc0 += h2f((unsigned short)BUF[i_]);               \
        }
#define CONSUME_TAIL(BUF, B)                                                \
        _Pragma("unroll")                                                   \
        for (int i_ = 0; i_ < 16; ++i_) {                                   \
            if ((B) + i_ < blen) {                                          \
                flushes(base + (B) + i_);                                   \
                if (i_ & 1) acc1 += h2f((unsigned short)BUF[i_]);           \
                else        acc0 += h2f((unsigned short)BUF[i_]);           \
            }                                                               \
        }

        int base = E0;
        unsigned rec = 0;
        if (base < E1 && lane < E1 - base) rec = srt[base + lane];
        while (base < E1) {
            const int blen = min(64, E1 - base);
            const int nbase = base + 64;
            unsigned recn = 0;
            if (nbase < E1) {
                // asm prefetch of next srt chunk: uniform SGPR base + per-lane
                // clamped VGPR byte offset. Drained by this chunk's last WAIT0.
                int ei = nbase + lane;
                if (ei > E1 - 1) ei = E1 - 1;
                unsigned eoff = (unsigned)ei << 2;
                asm volatile("global_load_dword %0, %1, %2"
                             : "=v"(recn) : "v"(eoff), "s"(srt));
            }

            const bool m1 = blen > 16, m2 = blen > 32, m3 = blen > 48;
            // batch 0 -> GA (junk-safe: lanes >= blen hold rec=0 -> row 0)
            ISSUE16(GA, rec, 0);
            if (m1) { ISSUE16(GB, rec, 16); WAIT16; } else WAIT0;
            SB;
            if (blen >= 16) { CONSUME_FULL(GA, 0); } else { CONSUME_TAIL(GA, 0); }
            if (m1) {
                if (m2) { ISSUE16(GA, rec, 32); WAIT16; } else WAIT0;
                SB;
                if (blen >= 32) { CONSUME_FULL(GB, 16); } else { CONSUME_TAIL(GB, 16); }
            }
            if (m2) {
                if (m3) { ISSUE16(GB, rec, 48); WAIT16; } else WAIT0;
                SB;
                if (blen >= 48) { CONSUME_FULL(GA, 32); } else { CONSUME_TAIL(GA, 32); }
            }
            if (m3) {
                WAIT0;
                SB;
                if (blen >= 64) { CONSUME_FULL(GB, 48); } else { CONSUME_TAIL(GB, 48); }
            }
            base = nbase;
            // every path above ends in WAIT0+SB, so recn is complete here and
            // this copy cannot be scheduled above that fence.
            rec = recn;
        }
#undef ISSUE16
#undef WAIT16
#undef WAIT0
#undef SB
#undef CONSUME_FULL
#undef CONSUME_TAIL
        flushes(E1);
        while (R < 32) {   // drain trailing empty segments
            float sc = __uint_as_float(
                __builtin_amdgcn_readlane(__float_as_uint(rsc), R));
            Atile[(w * 4 + (R >> 3)) * 600 + 64 + (R & 7) * 64 + lane] =
                f2h((acc0 + acc1) * sc);
            acc0 = 0.f; acc1 = 0.f;
            ++R;
        }
    }

    __syncthreads();

    // ---- MFMA dense phase: wave w = j-tile w ----
    constexpr int JPW = DOUT / 16;       // 4 (DOUT=64) or 2 (DOUT=32)
    if (JPW == 2 && w >= 2) return;      // DOUT=32: waves 2,3 done (after barrier)

    const int j = w * 16 + l16;
    f32x4 d = {0.f, 0.f, 0.f, 0.f};
    const unsigned short* arow = &Atile[l16 * 600];
#pragma unroll
    for (int c = 0; c < 9; ++c) {
        half8 a0 = *(const half8*)(arow + c * 64 + quad * 8);
        half8 a1 = *(const half8*)(arow + c * 64 + 32 + quad * 8);
        half8 b0 = *(const half8*)&wb[c * DOUT * 72 + j * 72 + quad * 8];
        half8 b1 = *(const half8*)&wb[c * DOUT * 72 + j * 72 + 32 + quad * 8];
        d = __builtin_amdgcn_mfma_f32_16x16x32_f16(a0, b0, d, 0, 0, 0);
        d = __builtin_amdgcn_mfma_f32_16x16x32_f16(a1, b1, d, 0, 0, 0);
    }

    // epilogue: C/D layout col = l16 (j), row = quad*4 + reg (node within tile)
    const float bj = bias[j];
#pragma unroll
    for (int r = 0; r < 4; ++r) {
        const int node = nbt + quad * 4 + r;
        if (node < n_nodes) {
            float v = d[r] + bj;
            if (RELU) v = fmaxf(v, 0.0f);
            if (OUTH) outh[(size_t)node * 64 + j] = f2h(v);
            else      outf[(size_t)node * DOUT + j] = v;
        }
    }
}

extern "C" void kernel_launch(void* const* d_in, const int* in_sizes, int n_in,
                              void* d_out, int out_size, void* d_ws, size_t ws_size,
                              hipStream_t stream) {
    const float* x     = (const float*)d_in[0];
    const float* W1    = (const float*)d_in[1];
    const float* root1 = (const float*)d_in[2];
    const float* b1    = (const float*)d_in[3];
    const float* W2    = (const float*)d_in[4];
    const float* root2 = (const float*)d_in[5];
    const float* b2    = (const float*)d_in[6];
    const int*   src   = (const int*)d_in[7];
    const int*   dst   = (const int*)d_in[8];
    const int*   et    = (const int*)d_in[9];

    const int N = in_sizes[0] / 64;
    const int E = in_sizes[7];
    const int KEYS = N * 8;

    char* p = (char*)d_ws;
    auto alloc = [&](size_t bytes) {
        char* r = p;
        p += (bytes + 15) & ~(size_t)15;
        return r;
    };
    unsigned* srt       = (unsigned*)alloc((size_t)E * 4);
    int* hist           = (int*)alloc((size_t)KEYS * 4);
    int* bstart         = (int*)alloc((size_t)(KEYS + 1) * 4);
    int* partial        = (int*)alloc(256 * 4);
    int* pscan          = (int*)alloc(256 * 4);
    unsigned short* wb1 = (unsigned short*)alloc((size_t)9 * 64 * 72 * 2);
    unsigned short* wb2 = (unsigned short*)alloc((size_t)9 * 32 * 72 * 2);
    unsigned short* xh  = (unsigned short*)alloc((size_t)N * 64 * 2);
    unsigned short* h   = (unsigned short*)alloc((size_t)N * 64 * 2);

    const int n8 = N * 8;                 // xprep items
    const int nhist4 = KEYS / 4;          // hist zero items (int4)
    const int prep_items = n8 + 9 * 64 * 64 + 9 * 64 * 32 + nhist4;
    prep_kernel<<<(prep_items + 255) / 256, 256, 0, stream>>>(
        x, xh, n8, W1, root1, wb1, W2, root2, wb2, hist, nhist4);

    hist8_kernel<<<(E + 255) / 256, 256, 0, stream>>>(dst, et, hist, E);
    const int nscan = (KEYS + SCAN_TILE - 1) / SCAN_TILE;
    scanA_kernel<<<nscan, 1024, 0, stream>>>(hist, bstart, partial, KEYS);
    scanB_kernel<<<1, 64, 0, stream>>>(partial, pscan, bstart + KEYS, nscan);
    scatter_kernel<<<(E + 255) / 256, 256, 0, stream>>>(
        src, dst, et, hist, bstart, pscan, srt, E);

    // layer 1: fused agg+dense over xh -> h (relu, f16)
    fused_kernel<64, 1, 1><<<(N + 15) / 16, 256, 0, stream>>>(
        xh, srt, bstart, pscan, wb1, b1, nullptr, h, N, E);
    // layer 2: fused agg+dense over h -> out (fp32)
    fused_kernel<32, 0, 0><<<(N + 15) / 16, 256, 0, stream>>>(
        h, srt, bstart, pscan, wb2, b2, (float*)d_out, nullptr, N, E);
}

// Round 10
// 341.397 us; speedup vs baseline: 1.0389x; 1.0389x over previous
//
#include <hip/hip_runtime.h>

typedef _Float16 half8 __attribute__((ext_vector_type(8)));
typedef __attribute__((ext_vector_type(4))) float f32x4;

__device__ __forceinline__ unsigned short f2h(float f) {
    _Float16 h = (_Float16)f;
    return *(unsigned short*)&h;
}
__device__ __forceinline__ float h2f(unsigned short u) {
    _Float16 h = *(_Float16*)&u;
    return (float)h;
}

// ---------- merged prep: x->f16, W1/W2 images, hist zero ----------

__device__ __forceinline__ void wprep_body(
    const float* __restrict__ W, const float* __restrict__ root,
    unsigned short* __restrict__ wb, int dout, int idx)
{
    int c = idx / (64 * dout);
    int rme = idx % (64 * dout);
    int kk = rme / dout;
    int j = rme % dout;
    float f = (c == 0) ? root[kk * dout + j]
                       : W[(size_t)(c - 1) * 64 * dout + kk * dout + j];
    wb[(size_t)c * dout * 72 + (size_t)j * 72 + kk] = f2h(f);
}

__global__ __launch_bounds__(256) void prep_kernel(
    const float* __restrict__ x, unsigned short* __restrict__ xh, int n8,
    const float* __restrict__ W1, const float* __restrict__ root1,
    unsigned short* __restrict__ wb1,
    const float* __restrict__ W2, const float* __restrict__ root2,
    unsigned short* __restrict__ wb2,
    int* __restrict__ hist, int nhist4)
{
    int id = blockIdx.x * 256 + threadIdx.x;
    if (id < n8) {                       // x -> f16, 8 elems/thread
        const f32x4* p = (const f32x4*)(x + (size_t)id * 8);
        f32x4 u = p[0], v = p[1];
        half8 o;
#pragma unroll
        for (int j = 0; j < 4; ++j) {
            o[j] = (_Float16)u[j];
            o[j + 4] = (_Float16)v[j];
        }
        *(half8*)(xh + (size_t)id * 8) = o;
        return;
    }
    id -= n8;
    if (id < 9 * 64 * 64) { wprep_body(W1, root1, wb1, 64, id); return; }
    id -= 9 * 64 * 64;
    if (id < 9 * 64 * 32) { wprep_body(W2, root2, wb2, 32, id); return; }
    id -= 9 * 64 * 32;
    if (id < nhist4) ((int4*)hist)[id] = make_int4(0, 0, 0, 0);
}

// ---------- preprocessing: counting sort by key = dst*8 + rel ----------

__global__ __launch_bounds__(256) void hist8_kernel(
    const int* __restrict__ dst, const int* __restrict__ et,
    int* __restrict__ hist, int E)
{
    int e = blockIdx.x * 256 + threadIdx.x;
    if (e < E) atomicAdd(&hist[dst[e] * 8 + et[e]], 1);
}

#define SCAN_TILE 4096
__global__ __launch_bounds__(1024) void scanA_kernel(
    const int* __restrict__ hist, int* __restrict__ bstart,
    int* __restrict__ partial, int nkeys)
{
    __shared__ int wsum[16];
    const int t = threadIdx.x;
    const int lane = t & 63, w = t >> 6;
    const int base = blockIdx.x * SCAN_TILE + t * 4;
    int v[4];
    int s = 0;
#pragma unroll
    for (int i = 0; i < 4; ++i) {
        v[i] = (base + i < nkeys) ? hist[base + i] : 0;
        s += v[i];
    }
    int inc = s;
#pragma unroll
    for (int off = 1; off < 64; off <<= 1) {
        int u = __shfl_up(inc, off);
        if (lane >= off) inc += u;
    }
    if (lane == 63) wsum[w] = inc;
    __syncthreads();
    if (w == 0 && lane < 16) {
        int ws = wsum[lane];
        int winc = ws;
#pragma unroll
        for (int off = 1; off < 16; off <<= 1) {
            int u = __shfl_up(winc, off);
            if (lane >= off) winc += u;
        }
        wsum[lane] = winc - ws;   // exclusive
    }
    __syncthreads();
    int run = wsum[w] + (inc - s);
#pragma unroll
    for (int i = 0; i < 4; ++i) {
        if (base + i < nkeys) bstart[base + i] = run;
        run += v[i];
    }
    if (t == 1023) partial[blockIdx.x] = run;   // block total
}

__global__ __launch_bounds__(64) void scanB_kernel(
    const int* __restrict__ partial, int* __restrict__ pscan,
    int* __restrict__ bstart_end, int nblk)
{
    const int lane = threadIdx.x;
    int running = 0;
    for (int b = 0; b < nblk; b += 64) {
        int i = b + lane;
        int o = (i < nblk) ? partial[i] : 0;
        int v = o;
#pragma unroll
        for (int off = 1; off < 64; off <<= 1) {
            int u = __shfl_up(v, off);
            if (lane >= off) v += u;
        }
        if (i < nblk) pscan[i] = running + v - o;
        running += __shfl(v, 63);
    }
    if (lane == 0) *bstart_end = running;   // == E
}

// scatter: pos = bstart[key] + pscan + (atomicSub(hist)-1).
// Within-segment order is arbitrary (sum is order-independent); hist is dead
// after scanA, so it doubles as the cursor -- no rank array at all.
__global__ __launch_bounds__(256) void scatter_kernel(
    const int* __restrict__ src, const int* __restrict__ dst,
    const int* __restrict__ et, int* __restrict__ hist,
    const int* __restrict__ bstart, const int* __restrict__ pscan,
    unsigned* __restrict__ srt, int E)
{
    int e = blockIdx.x * 256 + threadIdx.x;
    if (e < E) {
        int key = dst[e] * 8 + et[e];
        int r = atomicSub(&hist[key], 1) - 1;
        srt[bstart[key] + pscan[key >> 12] + r] = (unsigned)src[e];
    }
}

// ---------- fused layer: aggregate means into LDS A-tile, then MFMA dense ----------
// Block = 256 threads (4 waves) = 16 nodes; wave w owns 4 nodes (32 segments).
// Agg: lane = feature; per edge one SGPR-base 128B-row gather via asm-volatile
// global_load_ushort with counted s_waitcnt vmcnt(16) + sched_barrier(0).
// ROUND-9 BUG FIX: asm outputs went into C ARRAYS (GA[16]/GB[16]) which the
// allocator demoted to SCRATCH (rocprof: VGPR_Count=32 -- impossible if the 32
// buffers were registers). Every edge then paid a scratch round-trip and the
// counted-vmcnt pipeline was dead (82us, identical to no-asm). Now the 32
// buffer values are INDIVIDUALLY NAMED scalars (ga0..ga15, gb0..gb15) expanded
// by macros -- every access compile-time, nothing demotable (rule #20).

template <int DOUT, int RELU, int OUTH>
__global__ __launch_bounds__(256, 6) void fused_kernel(
    const unsigned short* __restrict__ tab,   // (N,64) f16 gather/self table
    const unsigned* __restrict__ srt,         // src per edge (sorted by dst*8+rel)
    const int* __restrict__ bstart,           // (N*8+1) LOCAL scan (pre-pscan)
    const int* __restrict__ pscan,            // per-4096-tile offsets
    const unsigned short* __restrict__ wb,    // (9, DOUT, 72) f16
    const float* __restrict__ bias,
    float* __restrict__ outf,                 // fp32 out (OUTH=0)
    unsigned short* __restrict__ outh,        // f16 out, stride 64 (OUTH=1)
    int n_nodes, int Etot)
{
    __shared__ __align__(16) unsigned short Atile[16 * 600];   // 19.2 KB

    const int t = threadIdx.x;
    const int w = t >> 6, lane = t & 63;
    const int quad = lane >> 4, l16 = lane & 15;
    const int nbt = blockIdx.x * 16;
    const int nb4 = nbt + w * 4;
    const int KEYS = n_nodes * 8;

    // ---- aggregation phase (wave-private rows) ----
    {
        const int nb0 = nb4 * 8;                          // 32 keys for this wave
        int idx = nb0 + lane; if (idx > KEYS) idx = KEYS;
        int lv;
        if (idx < KEYS) lv = bstart[idx] + pscan[idx >> 12];
        else            lv = Etot;
        const int E0 = __builtin_amdgcn_readlane(lv, 0);
        const int E1 = __builtin_amdgcn_readlane(lv, 32);

        // per-segment reciprocal counts (lanes 0..31 valid)
        int cntv = __shfl_down(lv, 1) - lv;
        float rsc = 1.0f / fmaxf((float)cntv, 1.0f);

        // self rows (chunk 0)
#pragma unroll
        for (int i = 0; i < 4; ++i) {
            int node = nb4 + i;
            unsigned short v = 0;
            if (node < n_nodes) v = tab[(size_t)node * 64 + lane];
            Atile[(w * 4 + i) * 600 + lane] = v;
        }

        float acc0 = 0.f, acc1 = 0.f;
        int R = 0;                                        // segment index 0..31
        int bnext = __builtin_amdgcn_readlane(lv, 1);

        auto flushes = [&](int eabs) {
            while (R < 32 && eabs == bnext) {
                float sc = __uint_as_float(
                    __builtin_amdgcn_readlane(__float_as_uint(rsc), R));
                Atile[(w * 4 + (R >> 3)) * 600 + 64 + (R & 7) * 64 + lane] =
                    f2h((acc0 + acc1) * sc);
                acc0 = 0.f; acc1 = 0.f;
                ++R;
                bnext = (R < 31) ? __builtin_amdgcn_readlane(lv, R + 1) : E1;
            }
        };

        const char* tabc = (const char*)tab;
        const unsigned voff = (unsigned)(lane << 1);
        // 32 NAMED gather registers (never arrays -> never scratch)
        unsigned ga0, ga1, ga2, ga3, ga4, ga5, ga6, ga7;
        unsigned ga8, ga9, ga10, ga11, ga12, ga13, ga14, ga15;
        unsigned gb0, gb1, gb2, gb3, gb4, gb5, gb6, gb7;
        unsigned gb8, gb9, gb10, gb11, gb12, gb13, gb14, gb15;

#define ISS(REG, I)                                                         \
        { int q_ = __builtin_amdgcn_readlane((int)rec, (I));                \
          const char* ap_ = tabc + ((size_t)(unsigned)q_ << 7);             \
          asm volatile("global_load_ushort %0, %1, %2"                      \
                       : "=v"(REG) : "v"(voff), "s"(ap_)); }
#define ISSUE_A(KB)                                                         \
        ISS(ga0,(KB)+0)   ISS(ga1,(KB)+1)   ISS(ga2,(KB)+2)   ISS(ga3,(KB)+3)   \
        ISS(ga4,(KB)+4)   ISS(ga5,(KB)+5)   ISS(ga6,(KB)+6)   ISS(ga7,(KB)+7)   \
        ISS(ga8,(KB)+8)   ISS(ga9,(KB)+9)   ISS(ga10,(KB)+10) ISS(ga11,(KB)+11) \
        ISS(ga12,(KB)+12) ISS(ga13,(KB)+13) ISS(ga14,(KB)+14) ISS(ga15,(KB)+15)
#define ISSUE_B(KB)                                                         \
        ISS(gb0,(KB)+0)   ISS(gb1,(KB)+1)   ISS(gb2,(KB)+2)   ISS(gb3,(KB)+3)   \
        ISS(gb4,(KB)+4)   ISS(gb5,(KB)+5)   ISS(gb6,(KB)+6)   ISS(gb7,(KB)+7)   \
        ISS(gb8,(KB)+8)   ISS(gb9,(KB)+9)   ISS(gb10,(KB)+10) ISS(gb11,(KB)+11) \
        ISS(gb12,(KB)+12) ISS(gb13,(KB)+13) ISS(gb14,(KB)+14) ISS(gb15,(KB)+15)
#define WAIT16  asm volatile("s_waitcnt vmcnt(16)" ::: "memory")
#define WAIT0   asm volatile("s_waitcnt vmcnt(0)" ::: "memory")
#define SB      __builtin_amdgcn_sched_barrier(0)
// consume one edge: flush pending segment boundaries FIRST, then accumulate
#define CF(REG, EI, ACC)                                                    \
        { flushes(base + (EI)); ACC += h2f((unsigned short)(REG)); }
#define CT(REG, EI, ACC)                                                    \
        { if ((EI) < blen) { flushes(base + (EI));                          \
                             ACC += h2f((unsigned short)(REG)); } }
#define CONSUME_A(B, CM)                                                    \
        CM(ga0,(B)+0,acc0)   CM(ga1,(B)+1,acc1)   CM(ga2,(B)+2,acc0)        \
        CM(ga3,(B)+3,acc1)   CM(ga4,(B)+4,acc0)   CM(ga5,(B)+5,acc1)        \
        CM(ga6,(B)+6,acc0)   CM(ga7,(B)+7,acc1)   CM(ga8,(B)+8,acc0)        \
        CM(ga9,(B)+9,acc1)   CM(ga10,(B)+10,acc0) CM(ga11,(B)+11,acc1)      \
        CM(ga12,(B)+12,acc0) CM(ga13,(B)+13,acc1) CM(ga14,(B)+14,acc0)      \
        CM(ga15,(B)+15,acc1)
#define CONSUME_B(B, CM)                                                    \
        CM(gb0,(B)+0,acc0)   CM(gb1,(B)+1,acc1)   CM(gb2,(B)+2,acc0)        \
        CM(gb3,(B)+3,acc1)   CM(gb4,(B)+4,acc0)   CM(gb5,(B)+5,acc1)        \
        CM(gb6,(B)+6,acc0)   CM(gb7,(B)+7,acc1)   CM(gb8,(B)+8,acc0)        \
        CM(gb9,(B)+9,acc1)   CM(gb10,(B)+10,acc0) CM(gb11,(B)+11,acc1)      \
        CM(gb12,(B)+12,acc0) CM(gb13,(B)+13,acc1) CM(gb14,(B)+14,acc0)      \
        CM(gb15,(B)+15,acc1)

        int base = E0;
        unsigned rec = 0;
        if (base < E1 && lane < E1 - base) rec = srt[base + lane];
        while (base < E1) {
            const int blen = min(64, E1 - base);
            const int nbase = base + 64;
            unsigned recn = 0;
            if (nbase < E1) {
                // asm prefetch of next srt chunk: uniform SGPR base + per-lane
                // clamped VGPR byte offset. Drained by this chunk's last WAIT0.
                int ei = nbase + lane;
                if (ei > E1 - 1) ei = E1 - 1;
                unsigned eoff = (unsigned)ei << 2;
                asm volatile("global_load_dword %0, %1, %2"
                             : "=v"(recn) : "v"(eoff), "s"(srt));
            }

            const bool m1 = blen > 16, m2 = blen > 32, m3 = blen > 48;
            // batch 0 -> A (junk-safe: lanes >= blen hold rec=0 -> row 0)
            ISSUE_A(0);
            if (m1) { ISSUE_B(16); WAIT16; } else WAIT0;
            SB;
            if (blen >= 16) { CONSUME_A(0, CF) } else { CONSUME_A(0, CT) }
            if (m1) {
                if (m2) { ISSUE_A(32); WAIT16; } else WAIT0;
                SB;
                if (blen >= 32) { CONSUME_B(16, CF) } else { CONSUME_B(16, CT) }
            }
            if (m2) {
                if (m3) { ISSUE_B(48); WAIT16; } else WAIT0;
                SB;
                if (blen >= 48) { CONSUME_A(32, CF) } else { CONSUME_A(32, CT) }
            }
            if (m3) {
                WAIT0;
                SB;
                if (blen >= 64) { CONSUME_B(48, CF) } else { CONSUME_B(48, CT) }
            }
            base = nbase;
            // every path above ends in a wait that also drained recn, and SB
            // fences scheduling -- rec=recn is safe here.
            rec = recn;
        }
#undef ISS
#undef ISSUE_A
#undef ISSUE_B
#undef WAIT16
#undef WAIT0
#undef SB
#undef CF
#undef CT
#undef CONSUME_A
#undef CONSUME_B
        flushes(E1);
        while (R < 32) {   // drain trailing empty segments
            float sc = __uint_as_float(
                __builtin_amdgcn_readlane(__float_as_uint(rsc), R));
            Atile[(w * 4 + (R >> 3)) * 600 + 64 + (R & 7) * 64 + lane] =
                f2h((acc0 + acc1) * sc);
            acc0 = 0.f; acc1 = 0.f;
            ++R;
        }
    }

    __syncthreads();

    // ---- MFMA dense phase: wave w = j-tile w ----
    constexpr int JPW = DOUT / 16;       // 4 (DOUT=64) or 2 (DOUT=32)
    if (JPW == 2 && w >= 2) return;      // DOUT=32: waves 2,3 done (after barrier)

    const int j = w * 16 + l16;
    f32x4 d = {0.f, 0.f, 0.f, 0.f};
    const unsigned short* arow = &Atile[l16 * 600];
#pragma unroll
    for (int c = 0; c < 9; ++c) {
        half8 a0 = *(const half8*)(arow + c * 64 + quad * 8);
        half8 a1 = *(const half8*)(arow + c * 64 + 32 + quad * 8);
        half8 b0 = *(const half8*)&wb[c * DOUT * 72 + j * 72 + quad * 8];
        half8 b1 = *(const half8*)&wb[c * DOUT * 72 + j * 72 + 32 + quad * 8];
        d = __builtin_amdgcn_mfma_f32_16x16x32_f16(a0, b0, d, 0, 0, 0);
        d = __builtin_amdgcn_mfma_f32_16x16x32_f16(a1, b1, d, 0, 0, 0);
    }

    // epilogue: C/D layout col = l16 (j), row = quad*4 + reg (node within tile)
    const float bj = bias[j];
#pragma unroll
    for (int r = 0; r < 4; ++r) {
        const int node = nbt + quad * 4 + r;
        if (node < n_nodes) {
            float v = d[r] + bj;
            if (RELU) v = fmaxf(v, 0.0f);
            if (OUTH) outh[(size_t)node * 64 + j] = f2h(v);
            else      outf[(size_t)node * DOUT + j] = v;
        }
    }
}

extern "C" void kernel_launch(void* const* d_in, const int* in_sizes, int n_in,
                              void* d_out, int out_size, void* d_ws, size_t ws_size,
                              hipStream_t stream) {
    const float* x     = (const float*)d_in[0];
    const float* W1    = (const float*)d_in[1];
    const float* root1 = (const float*)d_in[2];
    const float* b1    = (const float*)d_in[3];
    const float* W2    = (const float*)d_in[4];
    const float* root2 = (const float*)d_in[5];
    const float* b2    = (const float*)d_in[6];
    const int*   src   = (const int*)d_in[7];
    const int*   dst   = (const int*)d_in[8];
    const int*   et    = (const int*)d_in[9];

    const int N = in_sizes[0] / 64;
    const int E = in_sizes[7];
    const int KEYS = N * 8;

    char* p = (char*)d_ws;
    auto alloc = [&](size_t bytes) {
        char* r = p;
        p += (bytes + 15) & ~(size_t)15;
        return r;
    };
    unsigned* srt       = (unsigned*)alloc((size_t)E * 4);
    int* hist           = (int*)alloc((size_t)KEYS * 4);
    int* bstart         = (int*)alloc((size_t)(KEYS + 1) * 4);
    int* partial        = (int*)alloc(256 * 4);
    int* pscan          = (int*)alloc(256 * 4);
    unsigned short* wb1 = (unsigned short*)alloc((size_t)9 * 64 * 72 * 2);
    unsigned short* wb2 = (unsigned short*)alloc((size_t)9 * 32 * 72 * 2);
    unsigned short* xh  = (unsigned short*)alloc((size_t)N * 64 * 2);
    unsigned short* h   = (unsigned short*)alloc((size_t)N * 64 * 2);

    const int n8 = N * 8;                 // xprep items
    const int nhist4 = KEYS / 4;          // hist zero items (int4)
    const int prep_items = n8 + 9 * 64 * 64 + 9 * 64 * 32 + nhist4;
    prep_kernel<<<(prep_items + 255) / 256, 256, 0, stream>>>(
        x, xh, n8, W1, root1, wb1, W2, root2, wb2, hist, nhist4);

    hist8_kernel<<<(E + 255) / 256, 256, 0, stream>>>(dst, et, hist, E);
    const int nscan = (KEYS + SCAN_TILE - 1) / SCAN_TILE;
    scanA_kernel<<<nscan, 1024, 0, stream>>>(hist, bstart, partial, KEYS);
    scanB_kernel<<<1, 64, 0, stream>>>(partial, pscan, bstart + KEYS, nscan);
    scatter_kernel<<<(E + 255) / 256, 256, 0, stream>>>(
        src, dst, et, hist, bstart, pscan, srt, E);

    // layer 1: fused agg+dense over xh -> h (relu, f16)
    fused_kernel<64, 1, 1><<<(N + 15) / 16, 256, 0, stream>>>(
        xh, srt, bstart, pscan, wb1, b1, nullptr, h, N, E);
    // layer 2: fused agg+dense over h -> out (fp32)
    fused_kernel<32, 0, 0><<<(N + 15) / 16, 256, 0, stream>>>(
        h, srt, bstart, pscan, wb2, b2, (float*)d_out, nullptr, N, E);
}